// Round 1
// baseline (497.552 us; speedup 1.0000x reference)
//
#include <hip/hip_runtime.h>
#include <stdint.h>

#define B_ 4
#define S_ 2048
#define H_ 1024
#define NH_ 16
#define HD_ 64

typedef __bf16 bf16x8 __attribute__((ext_vector_type(8)));
typedef unsigned short u16x8 __attribute__((ext_vector_type(8)));
typedef float f32x4 __attribute__((ext_vector_type(4)));

__device__ __forceinline__ unsigned short f2bf(float x) {
  union { float f; unsigned u; } c; c.f = x;
  unsigned r = (c.u + 0x7FFFu + ((c.u >> 16) & 1u)) >> 16;
  return (unsigned short)r;
}

__device__ __forceinline__ void gload16(const unsigned short* g, unsigned short* lds) {
  __builtin_amdgcn_global_load_lds((const __attribute__((address_space(1))) void*)g,
                                   (__attribute__((address_space(3))) void*)lds, 16, 0, 0);
}

// ---------------- fp32 -> bf16 cast ----------------
__global__ __launch_bounds__(256) void cvt_kernel(const float* __restrict__ src,
                                                  unsigned short* __restrict__ dst, int n) {
  int i = (blockIdx.x * blockDim.x + threadIdx.x) * 4;
  if (i < n) {
    float4 v = *reinterpret_cast<const float4*>(src + i);
    ushort4 o;
    o.x = f2bf(v.x); o.y = f2bf(v.y); o.z = f2bf(v.z); o.w = f2bf(v.w);
    *reinterpret_cast<ushort4*>(dst + i) = o;
  }
}

// ---------------- bf16 GEMM, C[m,n] = sum_k A[m,k]*B[n,k] + bias[n] ----------------
// 128x128 tile, BK=32, 256 threads (4 waves, 2x2), global_load_lds staging.
template <bool BF16OUT>
__global__ __launch_bounds__(256) void gemm_bt(const unsigned short* __restrict__ A,
                                               const unsigned short* __restrict__ Bm,
                                               const float* __restrict__ bias,
                                               void* __restrict__ Cout,
                                               int M, int N, int K) {
  __shared__ unsigned short As[128 * 32];
  __shared__ unsigned short Bs[128 * 32];
  const int t = threadIdx.x;
  const int lane = t & 63;
  const int wv = t >> 6;
  const int wm = wv >> 1, wn = wv & 1;
  const int m0 = blockIdx.x * 128, n0 = blockIdx.y * 128;
  const int l15 = lane & 15, g8 = (lane >> 4) * 8;

  f32x4 acc[4][4];
#pragma unroll
  for (int i = 0; i < 4; ++i)
#pragma unroll
    for (int j = 0; j < 4; ++j) { f32x4 z = {0.f, 0.f, 0.f, 0.f}; acc[i][j] = z; }

  const int rowA = t >> 2;           // 0..63
  const int colA = (t & 3) * 8;      // 0,8,16,24
  const unsigned short* gA0 = A + (long)(m0 + rowA) * K + colA;
  const unsigned short* gA1 = A + (long)(m0 + 64 + rowA) * K + colA;
  const unsigned short* gB0 = Bm + (long)(n0 + rowA) * K + colA;
  const unsigned short* gB1 = Bm + (long)(n0 + 64 + rowA) * K + colA;
  unsigned short* ldsA0 = &As[wv * 512];
  unsigned short* ldsA1 = &As[2048 + wv * 512];
  unsigned short* ldsB0 = &Bs[wv * 512];
  unsigned short* ldsB1 = &Bs[2048 + wv * 512];

  for (int k0 = 0; k0 < K; k0 += 32) {
    __syncthreads();
    gload16(gA0 + k0, ldsA0);
    gload16(gA1 + k0, ldsA1);
    gload16(gB0 + k0, ldsB0);
    gload16(gB1 + k0, ldsB1);
    __syncthreads();

    bf16x8 af[4], bfr[4];
#pragma unroll
    for (int i = 0; i < 4; ++i)
      af[i] = *reinterpret_cast<const bf16x8*>(&As[(wm * 64 + i * 16 + l15) * 32 + g8]);
#pragma unroll
    for (int j = 0; j < 4; ++j)
      bfr[j] = *reinterpret_cast<const bf16x8*>(&Bs[(wn * 64 + j * 16 + l15) * 32 + g8]);
#pragma unroll
    for (int i = 0; i < 4; ++i)
#pragma unroll
      for (int j = 0; j < 4; ++j)
        acc[i][j] = __builtin_amdgcn_mfma_f32_16x16x32_bf16(af[i], bfr[j], acc[i][j], 0, 0, 0);
  }

  const int r0 = (lane >> 4) * 4;
#pragma unroll
  for (int i = 0; i < 4; ++i)
#pragma unroll
    for (int j = 0; j < 4; ++j) {
      int col = n0 + wn * 64 + j * 16 + l15;
      float bv = bias[col];
#pragma unroll
      for (int r = 0; r < 4; ++r) {
        int row = m0 + wm * 64 + i * 16 + r0 + r;
        float v = acc[i][j][r] + bv;
        if (BF16OUT)
          ((unsigned short*)Cout)[(long)row * N + col] = f2bf(v);
        else
          ((float*)Cout)[(long)row * N + col] = v;
      }
    }
}

// ---------------- flash attention ----------------
// grid (S/64, NH, B), 256 threads. Wave w handles 16 q-rows. KV tile = 64.
__global__ __launch_bounds__(256) void attn_kernel(const unsigned short* __restrict__ Q,
                                                   const unsigned short* __restrict__ Kg,
                                                   const unsigned short* __restrict__ Vg,
                                                   const float* __restrict__ mask,
                                                   unsigned short* __restrict__ ctx) {
  __shared__ unsigned short Kt[64 * 72];    // [kv][d] padded
  __shared__ unsigned short VtT[64 * 72];   // [d][kv] padded (transposed)
  __shared__ unsigned short Ps[4 * 16 * 72];

  const int t = threadIdx.x, lane = t & 63, wv = t >> 6;
  const int h = blockIdx.y, b = blockIdx.z;
  const int q0 = blockIdx.x * 64 + wv * 16;
  const int l15 = lane & 15, g8 = (lane >> 4) * 8;
  const long headoff = (long)h * HD_;

  const unsigned short* Qrow = Q + ((long)(b * S_ + q0 + l15)) * H_ + headoff;
  bf16x8 aq0 = *reinterpret_cast<const bf16x8*>(Qrow + g8);
  bf16x8 aq1 = *reinterpret_cast<const bf16x8*>(Qrow + 32 + g8);

  f32x4 o[4];
  float m[4], lsum[4];
#pragma unroll
  for (int d = 0; d < 4; ++d) { f32x4 z = {0.f, 0.f, 0.f, 0.f}; o[d] = z; }
#pragma unroll
  for (int r = 0; r < 4; ++r) { m[r] = -3.0e38f; lsum[r] = 0.f; }

  unsigned short* Pw = &Ps[wv * 16 * 72];
  const float L2E = 1.44269504088896f;

  for (int kv0 = 0; kv0 < S_; kv0 += 64) {
    __syncthreads();
    // stage K and transposed V
#pragma unroll
    for (int it = 0; it < 2; ++it) {
      int job = t + it * 256;
      int row = job >> 3, cg = (job & 7) * 8;
      const unsigned short* kp = Kg + ((long)(b * S_ + kv0 + row)) * H_ + headoff + cg;
      const unsigned short* vp = Vg + ((long)(b * S_ + kv0 + row)) * H_ + headoff + cg;
      u16x8 kvv = *reinterpret_cast<const u16x8*>(kp);
      *reinterpret_cast<u16x8*>(&Kt[row * 72 + cg]) = kvv;
      u16x8 vvv = *reinterpret_cast<const u16x8*>(vp);
#pragma unroll
      for (int j = 0; j < 8; ++j) VtT[(cg + j) * 72 + row] = vvv[j];
    }
    __syncthreads();

    // QK^T -> s[4] tiles (16 q x 64 kv per wave)
    f32x4 s[4];
#pragma unroll
    for (int c = 0; c < 4; ++c) {
      f32x4 z = {0.f, 0.f, 0.f, 0.f};
      bf16x8 k0f = *reinterpret_cast<const bf16x8*>(&Kt[(c * 16 + l15) * 72 + g8]);
      bf16x8 k1f = *reinterpret_cast<const bf16x8*>(&Kt[(c * 16 + l15) * 72 + 32 + g8]);
      z = __builtin_amdgcn_mfma_f32_16x16x32_bf16(aq0, k0f, z, 0, 0, 0);
      z = __builtin_amdgcn_mfma_f32_16x16x32_bf16(aq1, k1f, z, 0, 0, 0);
      s[c] = z;
    }
    float bs[4];
#pragma unroll
    for (int c = 0; c < 4; ++c)
      bs[c] = (1.f - mask[b * S_ + kv0 + c * 16 + l15]) * -10000.f;
#pragma unroll
    for (int c = 0; c < 4; ++c)
#pragma unroll
      for (int r = 0; r < 4; ++r) s[c][r] = s[c][r] * 0.125f + bs[c];

    // online softmax per row
#pragma unroll
    for (int r = 0; r < 4; ++r) {
      float mx = fmaxf(fmaxf(s[0][r], s[1][r]), fmaxf(s[2][r], s[3][r]));
#pragma unroll
      for (int d = 1; d < 16; d <<= 1) mx = fmaxf(mx, __shfl_xor(mx, d));
      float mn = fmaxf(m[r], mx);
      float al = exp2f((m[r] - mn) * L2E);
      m[r] = mn;
      float ps = 0.f;
#pragma unroll
      for (int c = 0; c < 4; ++c) {
        float p = exp2f((s[c][r] - mn) * L2E);
        s[c][r] = p;
        ps += p;
      }
#pragma unroll
      for (int d = 1; d < 16; d <<= 1) ps += __shfl_xor(ps, d);
      lsum[r] = lsum[r] * al + ps;
#pragma unroll
      for (int dt = 0; dt < 4; ++dt) o[dt][r] *= al;
    }

    // P -> LDS (bf16), re-fragment for PV
#pragma unroll
    for (int c = 0; c < 4; ++c)
#pragma unroll
      for (int r = 0; r < 4; ++r)
        Pw[((lane >> 4) * 4 + r) * 72 + c * 16 + l15] = f2bf(s[c][r]);
    __syncthreads();

    bf16x8 pa0 = *reinterpret_cast<const bf16x8*>(&Pw[l15 * 72 + g8]);
    bf16x8 pa1 = *reinterpret_cast<const bf16x8*>(&Pw[l15 * 72 + 32 + g8]);
#pragma unroll
    for (int dt = 0; dt < 4; ++dt) {
      bf16x8 v0f = *reinterpret_cast<const bf16x8*>(&VtT[(dt * 16 + l15) * 72 + g8]);
      bf16x8 v1f = *reinterpret_cast<const bf16x8*>(&VtT[(dt * 16 + l15) * 72 + 32 + g8]);
      o[dt] = __builtin_amdgcn_mfma_f32_16x16x32_bf16(pa0, v0f, o[dt], 0, 0, 0);
      o[dt] = __builtin_amdgcn_mfma_f32_16x16x32_bf16(pa1, v1f, o[dt], 0, 0, 0);
    }
  }

  // epilogue
#pragma unroll
  for (int dt = 0; dt < 4; ++dt)
#pragma unroll
    for (int r = 0; r < 4; ++r) {
      float val = o[dt][r] / lsum[r];
      int q = q0 + (lane >> 4) * 4 + r;
      ctx[((long)(b * S_ + q)) * H_ + headoff + dt * 16 + l15] = f2bf(val);
    }
}

// ---------------- residual + LayerNorm ----------------
__global__ __launch_bounds__(256) void ln_kernel(const float* __restrict__ proj,
                                                 const float* __restrict__ hs,
                                                 const float* __restrict__ gam,
                                                 const float* __restrict__ bet,
                                                 float* __restrict__ out) {
  const int row = blockIdx.x;
  const int t = threadIdx.x;
  const long base = (long)row * H_ + t * 4;
  float4 a = *reinterpret_cast<const float4*>(proj + base);
  float4 hv = *reinterpret_cast<const float4*>(hs + base);
  float x0 = a.x + hv.x, x1 = a.y + hv.y, x2 = a.z + hv.z, x3 = a.w + hv.w;
  float s1 = x0 + x1 + x2 + x3;
  float s2 = x0 * x0 + x1 * x1 + x2 * x2 + x3 * x3;
#pragma unroll
  for (int off = 1; off < 64; off <<= 1) {
    s1 += __shfl_xor(s1, off);
    s2 += __shfl_xor(s2, off);
  }
  __shared__ float a1[4], a2[4];
  if ((t & 63) == 0) { a1[t >> 6] = s1; a2[t >> 6] = s2; }
  __syncthreads();
  float ts1 = a1[0] + a1[1] + a1[2] + a1[3];
  float ts2 = a2[0] + a2[1] + a2[2] + a2[3];
  float mu = ts1 * (1.0f / H_);
  float var = ts2 * (1.0f / H_) - mu * mu;
  float inv = rsqrtf(var + 1e-12f);
  float4 g = *reinterpret_cast<const float4*>(gam + t * 4);
  float4 bb = *reinterpret_cast<const float4*>(bet + t * 4);
  float4 ov;
  ov.x = (x0 - mu) * inv * g.x + bb.x;
  ov.y = (x1 - mu) * inv * g.y + bb.y;
  ov.z = (x2 - mu) * inv * g.z + bb.z;
  ov.w = (x3 - mu) * inv * g.w + bb.w;
  *reinterpret_cast<float4*>(out + base) = ov;
}

extern "C" void kernel_launch(void* const* d_in, const int* in_sizes, int n_in,
                              void* d_out, int out_size, void* d_ws, size_t ws_size,
                              hipStream_t stream) {
  const float* hs   = (const float*)d_in[0];
  const float* mask = (const float*)d_in[1];
  const float* Wq   = (const float*)d_in[2];
  const float* bq   = (const float*)d_in[3];
  const float* Wk   = (const float*)d_in[4];
  const float* bk   = (const float*)d_in[5];
  const float* Wv   = (const float*)d_in[6];
  const float* bv   = (const float*)d_in[7];
  const float* Wd   = (const float*)d_in[8];
  const float* bd   = (const float*)d_in[9];
  const float* lng  = (const float*)d_in[10];
  const float* lnb  = (const float*)d_in[11];
  float* out = (float*)d_out;

  char* ws = (char*)d_ws;
  const size_t SZ_X = (size_t)B_ * S_ * H_ * 2;   // 16 MB bf16
  const size_t SZ_W = (size_t)H_ * H_ * 2;        // 2 MB bf16
  unsigned short* Xb  = (unsigned short*)(ws);
  unsigned short* Wqb = (unsigned short*)(ws + SZ_X);
  unsigned short* Wkb = (unsigned short*)(ws + SZ_X + SZ_W);
  unsigned short* Wvb = (unsigned short*)(ws + SZ_X + 2 * SZ_W);
  unsigned short* Wdb = (unsigned short*)(ws + SZ_X + 3 * SZ_W);
  unsigned short* Qb  = (unsigned short*)(ws + SZ_X + 4 * SZ_W);
  unsigned short* Kb  = (unsigned short*)(ws + 2 * SZ_X + 4 * SZ_W);
  unsigned short* Vb  = (unsigned short*)(ws + 3 * SZ_X + 4 * SZ_W);
  unsigned short* Cxb = (unsigned short*)(ws + 4 * SZ_X + 4 * SZ_W);
  float* Proj         = (float*)(ws + 5 * SZ_X + 4 * SZ_W);

  const int NX = B_ * S_ * H_;  // 8388608
  const int NW = H_ * H_;       // 1048576

  cvt_kernel<<<NX / 1024, 256, 0, stream>>>(hs, Xb, NX);
  cvt_kernel<<<NW / 1024, 256, 0, stream>>>(Wq, Wqb, NW);
  cvt_kernel<<<NW / 1024, 256, 0, stream>>>(Wk, Wkb, NW);
  cvt_kernel<<<NW / 1024, 256, 0, stream>>>(Wv, Wvb, NW);
  cvt_kernel<<<NW / 1024, 256, 0, stream>>>(Wd, Wdb, NW);

  dim3 gg(B_ * S_ / 128, H_ / 128);  // (64, 8)
  gemm_bt<true><<<gg, 256, 0, stream>>>(Xb, Wqb, bq, Qb, B_ * S_, H_, H_);
  gemm_bt<true><<<gg, 256, 0, stream>>>(Xb, Wkb, bk, Kb, B_ * S_, H_, H_);
  gemm_bt<true><<<gg, 256, 0, stream>>>(Xb, Wvb, bv, Vb, B_ * S_, H_, H_);

  dim3 ga(S_ / 64, NH_, B_);  // (32, 16, 4)
  attn_kernel<<<ga, 256, 0, stream>>>(Qb, Kb, Vb, mask, Cxb);

  gemm_bt<false><<<gg, 256, 0, stream>>>(Cxb, Wdb, bd, Proj, B_ * S_, H_, H_);

  ln_kernel<<<B_ * S_, 256, 0, stream>>>(Proj, hs, lng, lnb, out);
}

// Round 2
// 497.410 us; speedup vs baseline: 1.0003x; 1.0003x over previous
//
#include <hip/hip_runtime.h>
#include <stdint.h>

#define B_ 4
#define S_ 2048
#define H_ 1024
#define NH_ 16
#define HD_ 64

typedef __bf16 bf16x8 __attribute__((ext_vector_type(8)));
typedef unsigned short u16x8 __attribute__((ext_vector_type(8)));
typedef float f32x4 __attribute__((ext_vector_type(4)));

__device__ __forceinline__ unsigned short f2bf(float x) {
  union { float f; unsigned u; } c; c.f = x;
  unsigned r = (c.u + 0x7FFFu + ((c.u >> 16) & 1u)) >> 16;
  return (unsigned short)r;
}

__device__ __forceinline__ void gload16(const unsigned short* g, unsigned short* lds) {
  __builtin_amdgcn_global_load_lds((const __attribute__((address_space(1))) void*)g,
                                   (__attribute__((address_space(3))) void*)lds, 16, 0, 0);
}

// ---------------- fp32 -> bf16 cast ----------------
__global__ __launch_bounds__(256) void cvt_kernel(const float* __restrict__ src,
                                                  unsigned short* __restrict__ dst, int n) {
  int i = (blockIdx.x * blockDim.x + threadIdx.x) * 4;
  if (i < n) {
    float4 v = *reinterpret_cast<const float4*>(src + i);
    ushort4 o;
    o.x = f2bf(v.x); o.y = f2bf(v.y); o.z = f2bf(v.z); o.w = f2bf(v.w);
    *reinterpret_cast<ushort4*>(dst + i) = o;
  }
}

// ---------------- bf16 GEMM, C[m,n] = sum_k A[m,k]*B[n,k] + bias[n] ----------------
// 128x128 tile, BK=32, 256 threads (4 waves, 2x2), global_load_lds staging.
template <bool BF16OUT>
__global__ __launch_bounds__(256) void gemm_bt(const unsigned short* __restrict__ A,
                                               const unsigned short* __restrict__ Bm,
                                               const float* __restrict__ bias,
                                               void* __restrict__ Cout,
                                               int M, int N, int K) {
  __shared__ unsigned short As[128 * 32];
  __shared__ unsigned short Bs[128 * 32];
  const int t = threadIdx.x;
  const int lane = t & 63;
  const int wv = t >> 6;
  const int wm = wv >> 1, wn = wv & 1;
  const int m0 = blockIdx.x * 128, n0 = blockIdx.y * 128;
  const int l15 = lane & 15, g8 = (lane >> 4) * 8;

  f32x4 acc[4][4];
#pragma unroll
  for (int i = 0; i < 4; ++i)
#pragma unroll
    for (int j = 0; j < 4; ++j) { f32x4 z = {0.f, 0.f, 0.f, 0.f}; acc[i][j] = z; }

  const int rowA = t >> 2;           // 0..63
  const int colA = (t & 3) * 8;      // 0,8,16,24
  const unsigned short* gA0 = A + (long)(m0 + rowA) * K + colA;
  const unsigned short* gA1 = A + (long)(m0 + 64 + rowA) * K + colA;
  const unsigned short* gB0 = Bm + (long)(n0 + rowA) * K + colA;
  const unsigned short* gB1 = Bm + (long)(n0 + 64 + rowA) * K + colA;
  unsigned short* ldsA0 = &As[wv * 512];
  unsigned short* ldsA1 = &As[2048 + wv * 512];
  unsigned short* ldsB0 = &Bs[wv * 512];
  unsigned short* ldsB1 = &Bs[2048 + wv * 512];

  for (int k0 = 0; k0 < K; k0 += 32) {
    __syncthreads();
    gload16(gA0 + k0, ldsA0);
    gload16(gA1 + k0, ldsA1);
    gload16(gB0 + k0, ldsB0);
    gload16(gB1 + k0, ldsB1);
    __syncthreads();

    bf16x8 af[4], bfr[4];
#pragma unroll
    for (int i = 0; i < 4; ++i)
      af[i] = *reinterpret_cast<const bf16x8*>(&As[(wm * 64 + i * 16 + l15) * 32 + g8]);
#pragma unroll
    for (int j = 0; j < 4; ++j)
      bfr[j] = *reinterpret_cast<const bf16x8*>(&Bs[(wn * 64 + j * 16 + l15) * 32 + g8]);
#pragma unroll
    for (int i = 0; i < 4; ++i)
#pragma unroll
      for (int j = 0; j < 4; ++j)
        acc[i][j] = __builtin_amdgcn_mfma_f32_16x16x32_bf16(af[i], bfr[j], acc[i][j], 0, 0, 0);
  }

  const int r0 = (lane >> 4) * 4;
#pragma unroll
  for (int i = 0; i < 4; ++i)
#pragma unroll
    for (int j = 0; j < 4; ++j) {
      int col = n0 + wn * 64 + j * 16 + l15;
      float bv = bias[col];
#pragma unroll
      for (int r = 0; r < 4; ++r) {
        int row = m0 + wm * 64 + i * 16 + r0 + r;
        float v = acc[i][j][r] + bv;
        if (BF16OUT)
          ((unsigned short*)Cout)[(long)row * N + col] = f2bf(v);
        else
          ((float*)Cout)[(long)row * N + col] = v;
      }
    }
}

// ---------------- flash attention ----------------
// grid (S/64, NH, B), 256 threads. Wave w handles 16 q-rows. KV tile = 64.
__global__ __launch_bounds__(256) void attn_kernel(const unsigned short* __restrict__ Q,
                                                   const unsigned short* __restrict__ Kg,
                                                   const unsigned short* __restrict__ Vg,
                                                   const float* __restrict__ mask,
                                                   unsigned short* __restrict__ ctx) {
  __shared__ unsigned short Kt[64 * 72];    // [kv][d] padded
  __shared__ unsigned short VtT[64 * 72];   // [d][kv] padded (transposed)
  __shared__ unsigned short Ps[4 * 16 * 72];

  const int t = threadIdx.x, lane = t & 63, wv = t >> 6;
  const int h = blockIdx.y, b = blockIdx.z;
  const int q0 = blockIdx.x * 64 + wv * 16;
  const int l15 = lane & 15, g8 = (lane >> 4) * 8;
  const long headoff = (long)h * HD_;

  const unsigned short* Qrow = Q + ((long)(b * S_ + q0 + l15)) * H_ + headoff;
  bf16x8 aq0 = *reinterpret_cast<const bf16x8*>(Qrow + g8);
  bf16x8 aq1 = *reinterpret_cast<const bf16x8*>(Qrow + 32 + g8);

  f32x4 o[4];
  float m[4], lsum[4];
#pragma unroll
  for (int d = 0; d < 4; ++d) { f32x4 z = {0.f, 0.f, 0.f, 0.f}; o[d] = z; }
#pragma unroll
  for (int r = 0; r < 4; ++r) { m[r] = -3.0e38f; lsum[r] = 0.f; }

  unsigned short* Pw = &Ps[wv * 16 * 72];
  const float L2E = 1.44269504088896f;

  for (int kv0 = 0; kv0 < S_; kv0 += 64) {
    __syncthreads();
    // stage K and transposed V
#pragma unroll
    for (int it = 0; it < 2; ++it) {
      int job = t + it * 256;
      int row = job >> 3, cg = (job & 7) * 8;
      const unsigned short* kp = Kg + ((long)(b * S_ + kv0 + row)) * H_ + headoff + cg;
      const unsigned short* vp = Vg + ((long)(b * S_ + kv0 + row)) * H_ + headoff + cg;
      u16x8 kvv = *reinterpret_cast<const u16x8*>(kp);
      *reinterpret_cast<u16x8*>(&Kt[row * 72 + cg]) = kvv;
      u16x8 vvv = *reinterpret_cast<const u16x8*>(vp);
#pragma unroll
      for (int j = 0; j < 8; ++j) VtT[(cg + j) * 72 + row] = vvv[j];
    }
    __syncthreads();

    // QK^T -> s[4] tiles (16 q x 64 kv per wave)
    f32x4 s[4];
#pragma unroll
    for (int c = 0; c < 4; ++c) {
      f32x4 z = {0.f, 0.f, 0.f, 0.f};
      bf16x8 k0f = *reinterpret_cast<const bf16x8*>(&Kt[(c * 16 + l15) * 72 + g8]);
      bf16x8 k1f = *reinterpret_cast<const bf16x8*>(&Kt[(c * 16 + l15) * 72 + 32 + g8]);
      z = __builtin_amdgcn_mfma_f32_16x16x32_bf16(aq0, k0f, z, 0, 0, 0);
      z = __builtin_amdgcn_mfma_f32_16x16x32_bf16(aq1, k1f, z, 0, 0, 0);
      s[c] = z;
    }
    float bs[4];
#pragma unroll
    for (int c = 0; c < 4; ++c)
      bs[c] = (1.f - mask[b * S_ + kv0 + c * 16 + l15]) * -10000.f;
#pragma unroll
    for (int c = 0; c < 4; ++c)
#pragma unroll
      for (int r = 0; r < 4; ++r) s[c][r] = s[c][r] * 0.125f + bs[c];

    // online softmax per row
#pragma unroll
    for (int r = 0; r < 4; ++r) {
      float mx = fmaxf(fmaxf(s[0][r], s[1][r]), fmaxf(s[2][r], s[3][r]));
#pragma unroll
      for (int d = 1; d < 16; d <<= 1) mx = fmaxf(mx, __shfl_xor(mx, d));
      float mn = fmaxf(m[r], mx);
      float al = exp2f((m[r] - mn) * L2E);
      m[r] = mn;
      float ps = 0.f;
#pragma unroll
      for (int c = 0; c < 4; ++c) {
        float p = exp2f((s[c][r] - mn) * L2E);
        s[c][r] = p;
        ps += p;
      }
#pragma unroll
      for (int d = 1; d < 16; d <<= 1) ps += __shfl_xor(ps, d);
      lsum[r] = lsum[r] * al + ps;
#pragma unroll
      for (int dt = 0; dt < 4; ++dt) o[dt][r] *= al;
    }

    // P -> LDS (bf16), re-fragment for PV
#pragma unroll
    for (int c = 0; c < 4; ++c)
#pragma unroll
      for (int r = 0; r < 4; ++r)
        Pw[((lane >> 4) * 4 + r) * 72 + c * 16 + l15] = f2bf(s[c][r]);
    __syncthreads();

    bf16x8 pa0 = *reinterpret_cast<const bf16x8*>(&Pw[l15 * 72 + g8]);
    bf16x8 pa1 = *reinterpret_cast<const bf16x8*>(&Pw[l15 * 72 + 32 + g8]);
#pragma unroll
    for (int dt = 0; dt < 4; ++dt) {
      bf16x8 v0f = *reinterpret_cast<const bf16x8*>(&VtT[(dt * 16 + l15) * 72 + g8]);
      bf16x8 v1f = *reinterpret_cast<const bf16x8*>(&VtT[(dt * 16 + l15) * 72 + 32 + g8]);
      o[dt] = __builtin_amdgcn_mfma_f32_16x16x32_bf16(pa0, v0f, o[dt], 0, 0, 0);
      o[dt] = __builtin_amdgcn_mfma_f32_16x16x32_bf16(pa1, v1f, o[dt], 0, 0, 0);
    }
  }

  // epilogue
#pragma unroll
  for (int dt = 0; dt < 4; ++dt)
#pragma unroll
    for (int r = 0; r < 4; ++r) {
      float val = o[dt][r] / lsum[r];
      int q = q0 + (lane >> 4) * 4 + r;
      ctx[((long)(b * S_ + q)) * H_ + headoff + dt * 16 + l15] = f2bf(val);
    }
}

// ---------------- residual + LayerNorm ----------------
__global__ __launch_bounds__(256) void ln_kernel(const float* __restrict__ proj,
                                                 const float* __restrict__ hs,
                                                 const float* __restrict__ gam,
                                                 const float* __restrict__ bet,
                                                 float* __restrict__ out) {
  const int row = blockIdx.x;
  const int t = threadIdx.x;
  const long base = (long)row * H_ + t * 4;
  float4 a = *reinterpret_cast<const float4*>(proj + base);
  float4 hv = *reinterpret_cast<const float4*>(hs + base);
  float x0 = a.x + hv.x, x1 = a.y + hv.y, x2 = a.z + hv.z, x3 = a.w + hv.w;
  float s1 = x0 + x1 + x2 + x3;
  float s2 = x0 * x0 + x1 * x1 + x2 * x2 + x3 * x3;
#pragma unroll
  for (int off = 1; off < 64; off <<= 1) {
    s1 += __shfl_xor(s1, off);
    s2 += __shfl_xor(s2, off);
  }
  __shared__ float a1[4], a2[4];
  if ((t & 63) == 0) { a1[t >> 6] = s1; a2[t >> 6] = s2; }
  __syncthreads();
  float ts1 = a1[0] + a1[1] + a1[2] + a1[3];
  float ts2 = a2[0] + a2[1] + a2[2] + a2[3];
  float mu = ts1 * (1.0f / H_);
  float var = ts2 * (1.0f / H_) - mu * mu;
  float inv = rsqrtf(var + 1e-12f);
  float4 g = *reinterpret_cast<const float4*>(gam + t * 4);
  float4 bb = *reinterpret_cast<const float4*>(bet + t * 4);
  float4 ov;
  ov.x = (x0 - mu) * inv * g.x + bb.x;
  ov.y = (x1 - mu) * inv * g.y + bb.y;
  ov.z = (x2 - mu) * inv * g.z + bb.z;
  ov.w = (x3 - mu) * inv * g.w + bb.w;
  *reinterpret_cast<float4*>(out + base) = ov;
}

extern "C" void kernel_launch(void* const* d_in, const int* in_sizes, int n_in,
                              void* d_out, int out_size, void* d_ws, size_t ws_size,
                              hipStream_t stream) {
  const float* hs   = (const float*)d_in[0];
  const float* mask = (const float*)d_in[1];
  const float* Wq   = (const float*)d_in[2];
  const float* bq   = (const float*)d_in[3];
  const float* Wk   = (const float*)d_in[4];
  const float* bk   = (const float*)d_in[5];
  const float* Wv   = (const float*)d_in[6];
  const float* bv   = (const float*)d_in[7];
  const float* Wd   = (const float*)d_in[8];
  const float* bd   = (const float*)d_in[9];
  const float* lng  = (const float*)d_in[10];
  const float* lnb  = (const float*)d_in[11];
  float* out = (float*)d_out;

  char* ws = (char*)d_ws;
  const size_t SZ_X = (size_t)B_ * S_ * H_ * 2;   // 16 MB bf16
  const size_t SZ_W = (size_t)H_ * H_ * 2;        // 2 MB bf16
  unsigned short* Xb  = (unsigned short*)(ws);
  unsigned short* Wqb = (unsigned short*)(ws + SZ_X);
  unsigned short* Wkb = (unsigned short*)(ws + SZ_X + SZ_W);
  unsigned short* Wvb = (unsigned short*)(ws + SZ_X + 2 * SZ_W);
  unsigned short* Wdb = (unsigned short*)(ws + SZ_X + 3 * SZ_W);
  unsigned short* Qb  = (unsigned short*)(ws + SZ_X + 4 * SZ_W);
  unsigned short* Kb  = (unsigned short*)(ws + 2 * SZ_X + 4 * SZ_W);
  unsigned short* Vb  = (unsigned short*)(ws + 3 * SZ_X + 4 * SZ_W);
  unsigned short* Cxb = (unsigned short*)(ws + 4 * SZ_X + 4 * SZ_W);
  float* Proj         = (float*)(ws + 5 * SZ_X + 4 * SZ_W);

  const int NX = B_ * S_ * H_;  // 8388608
  const int NW = H_ * H_;       // 1048576

  cvt_kernel<<<NX / 1024, 256, 0, stream>>>(hs, Xb, NX);
  cvt_kernel<<<NW / 1024, 256, 0, stream>>>(Wq, Wqb, NW);
  cvt_kernel<<<NW / 1024, 256, 0, stream>>>(Wk, Wkb, NW);
  cvt_kernel<<<NW / 1024, 256, 0, stream>>>(Wv, Wvb, NW);
  cvt_kernel<<<NW / 1024, 256, 0, stream>>>(Wd, Wdb, NW);

  dim3 gg(B_ * S_ / 128, H_ / 128);  // (64, 8)
  gemm_bt<true><<<gg, 256, 0, stream>>>(Xb, Wqb, bq, Qb, B_ * S_, H_, H_);
  gemm_bt<true><<<gg, 256, 0, stream>>>(Xb, Wkb, bk, Kb, B_ * S_, H_, H_);
  gemm_bt<true><<<gg, 256, 0, stream>>>(Xb, Wvb, bv, Vb, B_ * S_, H_, H_);

  dim3 ga(S_ / 64, NH_, B_);  // (32, 16, 4)
  attn_kernel<<<ga, 256, 0, stream>>>(Qb, Kb, Vb, mask, Cxb);

  gemm_bt<false><<<gg, 256, 0, stream>>>(Cxb, Wdb, bd, Proj, B_ * S_, H_, H_);

  ln_kernel<<<B_ * S_, 256, 0, stream>>>(Proj, hs, lng, lnb, out);
}